// Round 23
// baseline (610.279 us; speedup 1.0000x reference)
//
#include <hip/hip_runtime.h>
#include <hip/hip_bf16.h>
#include <math.h>

// Swin block forward: B=2, IMG=128, E=256, NH=8, HD=32, WS=8, T=64, L=4, HID=1024
#define E_DIM 256
#define NPB 16384           // tokens per batch = 128*128
#define M_TOT 32768         // total tokens

typedef __attribute__((ext_vector_type(4))) float f32x4;
typedef __attribute__((ext_vector_type(8))) short s16x8;

__device__ inline unsigned short f2bu(float f) {       // fp32 -> bf16 via native cvt
  __hip_bfloat16 h = __float2bfloat16(f);
  return *reinterpret_cast<unsigned short*>(&h);
}
__device__ inline float bu2f(unsigned short u) {
  union { unsigned int i; float f; } x; x.i = ((unsigned int)u) << 16; return x.f;
}
__device__ inline void gload16(const void* g, void* l) {
  __builtin_amdgcn_global_load_lds(
      (const __attribute__((address_space(1))) void*)g,
      (__attribute__((address_space(3))) void*)l, 16, 0, 0);
}
// fast gelu (tanh form)
__device__ inline float fgelu(float v) {
  float u2 = 2.0f * v * (0.7978845608f + 0.0356774081f * v * v);
  u2 = fminf(u2, 30.0f);
  float e = __expf(u2);
  return v * (e / (e + 1.0f));
}

// ---------------- ALL weight conversions in ONE dispatch (3136 blocks)
__global__ __launch_bounds__(256) void wconv_all(
    const float* __restrict__ qkv_w, const float* __restrict__ proj_w,
    const float* __restrict__ w1,    const float* __restrict__ w2,
    const float* __restrict__ outw,
    unsigned short* __restrict__ qkvT, unsigned short* __restrict__ projT,
    unsigned short* __restrict__ w1T,  unsigned short* __restrict__ w2T,
    unsigned short* __restrict__ outwb)
{
  int bid = blockIdx.x;
  if (bid >= 3072) {                      // out_w cast
    int idx = (bid - 3072) * 1024 + threadIdx.x * 4;
    float4 v = *(const float4*)(outw + idx);
    ushort4 u; u.x = f2bu(v.x); u.y = f2bu(v.y); u.z = f2bu(v.z); u.w = f2bu(v.w);
    *(ushort4*)(outwb + idx) = u;
    return;
  }
  int layer = bid / 768, r = bid % 768;
  const float* W; unsigned short* Wt; int K, N, txt, tile;
  if (r < 192)      { W = qkv_w  + (size_t)layer*196608; Wt = qkvT + (size_t)layer*196608; K=256;  N=768;  txt=24; tile=r; }
  else if (r < 256) { W = proj_w + (size_t)layer*65536;  Wt = projT+ (size_t)layer*65536;  K=256;  N=256;  txt=8;  tile=r-192; }
  else if (r < 512) { W = w1     + (size_t)layer*262144; Wt = w1T  + (size_t)layer*262144; K=256;  N=1024; txt=32; tile=r-256; }
  else              { W = w2     + (size_t)layer*262144; Wt = w2T  + (size_t)layer*262144; K=1024; N=256;  txt=8;  tile=r-512; }
  int nb = (tile % txt) * 32, kb = (tile / txt) * 32;
  __shared__ float t[32][33];
  int tx = threadIdx.x & 31, ty = threadIdx.x >> 5;
  #pragma unroll
  for (int i = 0; i < 32; i += 8)
    t[ty + i][tx] = W[(size_t)(kb + ty + i) * N + nb + tx];
  __syncthreads();
  #pragma unroll
  for (int i = 0; i < 32; i += 8)
    Wt[(size_t)(nb + ty + i) * K + kb + tx] = f2bu(t[tx][ty + i]);
}

// ---------------- fused input embed + LN1(layer0)
__global__ __launch_bounds__(256) void embed_ln(
    const float* __restrict__ x, const float* __restrict__ in_w,
    const float* __restrict__ in_b, const float* __restrict__ pos,
    const float* __restrict__ g, const float* __restrict__ bta,
    float* __restrict__ seq, unsigned short* __restrict__ hb)
{
  __shared__ float ld[32][33];
  __shared__ float vbuf[32][260];
  __shared__ float2 st[32];
  const int n0 = blockIdx.x * 32;
  const int b = n0 >> 14, np = n0 & (NPB - 1);
  const int tx = threadIdx.x & 31, ty = threadIdx.x >> 5;

  float x0[4], x1[4], x2[4], sp[4] = {0,0,0,0}, qp[4] = {0,0,0,0};
  #pragma unroll
  for (int i = 0; i < 4; i++) {
    int n = np + ty + 8*i;
    x0[i] = x[(b*3 + 0)*NPB + n];
    x1[i] = x[(b*3 + 1)*NPB + n];
    x2[i] = x[(b*3 + 2)*NPB + n];
  }
  for (int ec = 0; ec < 8; ec++) {
    int e0 = ec * 32;
    #pragma unroll
    for (int i = 0; i < 4; i++)
      ld[ty + 8*i][tx] = pos[(size_t)(e0 + ty + 8*i) * NPB + np + tx];
    __syncthreads();
    #pragma unroll
    for (int i = 0; i < 4; i++) {
      int e = e0 + tx;
      float v = x0[i]*in_w[e*3+0] + x1[i]*in_w[e*3+1] + x2[i]*in_w[e*3+2]
              + in_b[e] + ld[tx][ty + 8*i];
      vbuf[ty + 8*i][e] = v;
      sp[i] += v; qp[i] += v * v;
    }
    __syncthreads();
  }
  #pragma unroll
  for (int i = 0; i < 4; i++) {
    #pragma unroll
    for (int off = 1; off < 32; off <<= 1) {
      sp[i] += __shfl_xor(sp[i], off);
      qp[i] += __shfl_xor(qp[i], off);
    }
    if (tx == 0) st[ty + 8*i] = (float2){sp[i], qp[i]};
  }
  __syncthreads();
  const int token = threadIdx.x >> 3, ch = threadIdx.x & 7;
  float2 sq = st[token];
  float mean = sq.x * (1.0f / 256.0f);
  float rstd = rsqrtf(sq.y * (1.0f / 256.0f) - mean * mean + 1e-5f);
  float* srow = seq + (size_t)(n0 + token) * 256;
  unsigned short* hrow = hb + (size_t)(n0 + token) * 256;
  #pragma unroll
  for (int u = 0; u < 8; u++) {
    int e = ch * 32 + u * 4;
    float4 v = *(float4*)&vbuf[token][e];
    *(float4*)(srow + e) = v;
    float4 gg = *(const float4*)(g + e);
    float4 bb = *(const float4*)(bta + e);
    ushort4 h;
    h.x = f2bu((v.x - mean) * rstd * gg.x + bb.x);
    h.y = f2bu((v.y - mean) * rstd * gg.y + bb.y);
    h.z = f2bu((v.z - mean) * rstd * gg.z + bb.z);
    h.w = f2bu((v.w - mean) * rstd * gg.w + bb.w);
    *(ushort4*)(hrow + e) = h;
  }
}

// swizzle helper: f(row) for chunk-XOR LDS layout
__device__ inline int rowf(int r) { return (r & 3) ^ ((r >> 2) & 3); }

// ---------------- FUSED QKV-GEMM + window attention: one block per window
template<int SHIFT>
__global__ __launch_bounds__(512) void qkv_attn(
    const unsigned short* __restrict__ hbuf, const unsigned short* __restrict__ qkvT,
    const float* __restrict__ qkv_b, unsigned short* __restrict__ hout)
{
  __shared__ unsigned short AQ[32768];   // 64KB: A[2048 chunks] + Q[t][256]; reused as P
  __shared__ unsigned short Ks[16384];   // 32KB: K[t][256] chunk-swizzled
  __shared__ unsigned short Vt[16384];   // 32KB: V^T [h][d 32][t 64] swizzled
  const int tid = threadIdx.x, lane = tid & 63, wc = tid >> 6;
  const int lc = lane & 15, lg = lane >> 4;
  const int wf = blockIdx.x;
  const int b = wf >> 8, win = wf & 255;
  const int wh = win >> 4, ww = win & 15;

  auto tok_of = [&](int t) -> int {
    int hs = wh * 8 + (t >> 3), ws = ww * 8 + (t & 7);
    if (SHIFT) { hs = (hs + 4) & 127; ws = (ws + 4) & 127; }
    return b * NPB + hs * 128 + ws;
  };
  auto reg_of = [&](int t) -> int {
    int hs = wh * 8 + (t >> 3), ws = ww * 8 + (t & 7);
    int a = (hs < 120) ? 0 : ((hs < 124) ? 1 : 2);
    int c = (ws < 120) ? 0 : ((ws < 124) ? 1 : 2);
    return a * 3 + c;
  };

  #pragma unroll
  for (int jj = 0; jj < 4; jj++) {
    int chunk = tid + jj * 512;
    int r = chunk >> 5, c = chunk & 31;
    int cg = (c & 24) | ((c & 7) ^ (r & 7));
    gload16(hbuf + (size_t)tok_of(r) * 256 + cg * 8, (char*)AQ + chunk * 16);
  }
  __syncthreads();

  const int fmap0 = 2*wc, fmap1 = 2*wc+1, fmap2 = 16+2*wc, fmap3 = 17+2*wc,
            fmap4 = 32+2*wc, fmap5 = 33+2*wc;
  int fmap[6] = {fmap0, fmap1, fmap2, fmap3, fmap4, fmap5};
  f32x4 acc[4][6];
  #pragma unroll
  for (int m = 0; m < 4; m++)
    #pragma unroll
    for (int j = 0; j < 6; j++)
      acc[m][j] = (f32x4){0.f, 0.f, 0.f, 0.f};

  const unsigned short* bb[6];
  #pragma unroll
  for (int j = 0; j < 6; j++)
    bb[j] = qkvT + (size_t)(fmap[j] * 16 + lc) * 256 + lg * 8;

  s16x8 bcur[6];
  #pragma unroll
  for (int j = 0; j < 6; j++) bcur[j] = *(const s16x8*)(bb[j]);

  #pragma unroll
  for (int t = 0; t < 8; t++) {
    s16x8 bnext[6];
    if (t < 7) {
      #pragma unroll
      for (int j = 0; j < 6; j++) bnext[j] = *(const s16x8*)(bb[j] + (t + 1) * 32);
    }
    s16x8 aF[4];
    #pragma unroll
    for (int m = 0; m < 4; m++) {
      int r = m * 16 + lc;
      int g = t * 4 + lg;
      int cc = (g & 24) | ((g & 7) ^ (r & 7));
      aF[m] = *(const s16x8*)(AQ + r * 256 + cc * 8);
    }
    #pragma unroll
    for (int m = 0; m < 4; m++)
      #pragma unroll
      for (int j = 0; j < 6; j++)
        acc[m][j] = __builtin_amdgcn_mfma_f32_16x16x32_bf16(aF[m], bcur[j], acc[m][j], 0, 0, 0);
    if (t < 7) {
      #pragma unroll
      for (int j = 0; j < 6; j++) bcur[j] = bnext[j];
    }
  }

  float bv[6];
  #pragma unroll
  for (int j = 0; j < 6; j++) bv[j] = qkv_b[fmap[j] * 16 + lc];
  const float scale = 0.17677669529663687f;

  #pragma unroll
  for (int j = 0; j < 6; j++) {
    int col = fmap[j] * 16 + lc;
    #pragma unroll
    for (int m = 0; m < 4; m++)
      #pragma unroll
      for (int r = 0; r < 4; r++) {
        int t = m * 16 + lg * 4 + r;
        float v = acc[m][j][r] + bv[j];
        if (j < 2) {                         // Q (fold softmax scale)
          int qc = col, c = qc >> 3;
          int cc = (c & 24) | ((c & 7) ^ (t & 7));
          AQ[16384 + t * 256 + cc * 8 + (qc & 7)] = f2bu(v * scale);
        } else if (j < 4) {                  // K
          int kc = col - 256, c = kc >> 3;
          int cc = (c & 24) | ((c & 7) ^ (t & 7));
          Ks[t * 256 + cc * 8 + (kc & 7)] = f2bu(v);
        } else {                             // V transposed: [wc][d][t]
          int d = col - 512 - wc * 32;
          int tc = (t >> 3) ^ (d & 7);
          Vt[wc * 2048 + d * 64 + tc * 8 + (t & 7)] = f2bu(v);
        }
      }
  }

  s16x8 qf[4], kf[4];
  #pragma unroll
  for (int m = 0; m < 4; m++) {
    int t = m * 16 + lc;
    int g = wc * 4 + lg;
    int cc = (g & 24) | ((g & 7) ^ (t & 7));
    qf[m] = *(const s16x8*)(AQ + 16384 + t * 256 + cc * 8);
    kf[m] = *(const s16x8*)(Ks + t * 256 + cc * 8);
  }
  __syncthreads();

  f32x4 sT[4][4];
  #pragma unroll
  for (int m = 0; m < 4; m++)
    #pragma unroll
    for (int qt = 0; qt < 4; qt++) {
      f32x4 z = (f32x4){0.f, 0.f, 0.f, 0.f};
      sT[m][qt] = __builtin_amdgcn_mfma_f32_16x16x32_bf16(kf[m], qf[qt], z, 0, 0, 0);
    }

  int qreg[4], kreg2[16];
  if (SHIFT) {
    #pragma unroll
    for (int qt = 0; qt < 4; qt++) qreg[qt] = reg_of(qt * 16 + lc);
    #pragma unroll
    for (int m = 0; m < 4; m++)
      #pragma unroll
      for (int r = 0; r < 4; r++) kreg2[m * 4 + r] = reg_of(m * 16 + lg * 4 + r);
  }

  unsigned short* Pl = AQ + wc * 4096;
  #pragma unroll
  for (int qt = 0; qt < 4; qt++) {
    float mx = -1e30f;
    #pragma unroll
    for (int m = 0; m < 4; m++)
      #pragma unroll
      for (int r = 0; r < 4; r++) {
        float s = sT[m][qt][r];
        if (SHIFT && qreg[qt] != kreg2[m * 4 + r]) s -= 100.0f;
        sT[m][qt][r] = s;
        mx = fmaxf(mx, s);
      }
    mx = fmaxf(mx, __shfl_xor(mx, 16));
    mx = fmaxf(mx, __shfl_xor(mx, 32));
    float sum = 0.f;
    #pragma unroll
    for (int m = 0; m < 4; m++)
      #pragma unroll
      for (int r = 0; r < 4; r++) {
        float p = __expf(sT[m][qt][r] - mx);
        sT[m][qt][r] = p;
        sum += p;
      }
    sum += __shfl_xor(sum, 16);
    sum += __shfl_xor(sum, 32);
    float inv = 1.0f / sum;
    int q = qt * 16 + lc;
    #pragma unroll
    for (int m = 0; m < 4; m++) {
      ushort4 pk;
      pk.x = f2bu(sT[m][qt][0] * inv);
      pk.y = f2bu(sT[m][qt][1] * inv);
      pk.z = f2bu(sT[m][qt][2] * inv);
      pk.w = f2bu(sT[m][qt][3] * inv);
      *(ushort4*)(Pl + ((q * 64 + m * 16 + lg * 4) ^ ((q & 7) << 3))) = pk;
    }
  }

  f32x4 oacc[4][2];
  #pragma unroll
  for (int qt = 0; qt < 4; qt++)
    #pragma unroll
    for (int n = 0; n < 2; n++)
      oacc[qt][n] = (f32x4){0.f, 0.f, 0.f, 0.f};
  #pragma unroll
  for (int kb = 0; kb < 2; kb++) {
    s16x8 pa[4], vb2[2];
    #pragma unroll
    for (int qt = 0; qt < 4; qt++) {
      int q = qt * 16 + lc;
      pa[qt] = *(const s16x8*)(Pl + ((q * 64 + kb * 32 + lg * 8) ^ ((q & 7) << 3)));
    }
    #pragma unroll
    for (int n = 0; n < 2; n++) {
      int d = n * 16 + lc;
      vb2[n] = *(const s16x8*)(Vt + wc * 2048 + d * 64 + (((kb * 4 + lg) ^ (d & 7)) * 8));
    }
    #pragma unroll
    for (int qt = 0; qt < 4; qt++)
      #pragma unroll
      for (int n = 0; n < 2; n++)
        oacc[qt][n] = __builtin_amdgcn_mfma_f32_16x16x32_bf16(pa[qt], vb2[n], oacc[qt][n], 0, 0, 0);
  }

  #pragma unroll
  for (int qt = 0; qt < 4; qt++)
    #pragma unroll
    for (int r = 0; r < 4; r++) {
      int q = qt * 16 + lg * 4 + r;
      unsigned short* ob = hout + (size_t)tok_of(q) * 256 + wc * 32;
      ob[lc]      = f2bu(oacc[qt][0][r]);
      ob[16 + lc] = f2bu(oacc[qt][1][r]);
    }
}

// ---------------- bf16 MFMA GEMM, 64x256 tile, BK=32, 8 waves (2x4 of 32x64)
// High-occupancy variant for latency-bound shapes (grid (M/64)x(N/256)).
template<int ACT, int OBF>
__global__ __launch_bounds__(512) void mgemm_b(
    const unsigned short* __restrict__ A, const unsigned short* __restrict__ Wt,
    const float* __restrict__ bias, void* __restrict__ Cv, int N, int K)
{
  __shared__ unsigned short Al[2][64 * 32];    // 8 KB
  __shared__ unsigned short Bl[2][256 * 32];   // 32 KB
  const int tid  = threadIdx.x;
  const int lane = tid & 63;
  const int wid  = tid >> 6;
  const int wr = wid >> 2, wc = wid & 3;       // 2x4 waves, 32x64 each
  const int nbx = N >> 8;
  const int bid = blockIdx.x;
  const int lt  = (bid & 7) * ((int)gridDim.x >> 3) + (bid >> 3);
  const int bn  = (lt % nbx) * 256, bm = (lt / nbx) * 64;

  f32x4 acc[2][4];
  #pragma unroll
  for (int m = 0; m < 2; m++)
    #pragma unroll
    for (int n = 0; n < 4; n++)
      acc[m][n] = (f32x4){0.f, 0.f, 0.f, 0.f};

  const int srow = tid >> 2;
  const int cs   = (tid & 3) ^ rowf(srow);
  const unsigned short* aSrc  = A  + (size_t)(bm + srow) * K + cs * 8;   // tid<256
  const unsigned short* bSrc0 = Wt + (size_t)(bn + srow) * K + cs * 8;
  const unsigned short* bSrc1 = Wt + (size_t)(bn + srow + 128) * K + cs * 8;

  const int slotx = (lane >> 4) ^ (lane & 3) ^ ((lane >> 2) & 3);
  const int aoff = (wr*32 + (lane & 15)) * 64 + slotx * 16;
  const int boff = (wc*64 + (lane & 15)) * 64 + slotx * 16;

  {
    if (tid < 256) gload16(aSrc, (char*)Al[0] + tid * 16);
    gload16(bSrc0, (char*)Bl[0] + tid * 16);
    gload16(bSrc1, (char*)Bl[0] + tid * 16 + 8192);
  }
  __syncthreads();

  const int nt = K >> 5;
  int cur = 0;
  for (int t = 0; t < nt; ++t) {
    if (t + 1 < nt) {
      int k0 = (t + 1) << 5;
      if (tid < 256) gload16(aSrc + k0, (char*)Al[cur ^ 1] + tid * 16);
      gload16(bSrc0 + k0, (char*)Bl[cur ^ 1] + tid * 16);
      gload16(bSrc1 + k0, (char*)Bl[cur ^ 1] + tid * 16 + 8192);
    }
    const char* ab = (const char*)Al[cur] + aoff;
    const char* bbp = (const char*)Bl[cur] + boff;
    s16x8 af[2], bf_[4];
    #pragma unroll
    for (int m = 0; m < 2; m++) af[m]  = *(const s16x8*)(ab + m * 1024);
    #pragma unroll
    for (int n = 0; n < 4; n++) bf_[n] = *(const s16x8*)(bbp + n * 1024);
    #pragma unroll
    for (int m = 0; m < 2; m++)
      #pragma unroll
      for (int n = 0; n < 4; n++)
        acc[m][n] = __builtin_amdgcn_mfma_f32_16x16x32_bf16(af[m], bf_[n], acc[m][n], 0, 0, 0);
    __syncthreads();
    cur ^= 1;
  }

  const int lc = lane & 15, lg = lane >> 4;
  float bv[4];
  #pragma unroll
  for (int n = 0; n < 4; n++) bv[n] = bias[bn + wc*64 + n*16 + lc];

  #pragma unroll
  for (int m = 0; m < 2; m++) {
    int row0 = bm + wr*32 + m*16 + lg * 4;
    #pragma unroll
    for (int n = 0; n < 4; n++) {
      int col = bn + wc*64 + n*16 + lc;
      #pragma unroll
      for (int j = 0; j < 4; j++) {
        int row = row0 + j;
        float v = acc[m][n][j] + bv[n];
        if (ACT) v = fgelu(v);
        if (OBF) ((unsigned short*)Cv)[(size_t)row * N + col] = f2bu(v);
        else     ((float*)Cv)[(size_t)row * N + col] = v;
      }
    }
  }
}

// ---------------- bf16 MFMA GEMM, 128x256 tile, BK=32, 8 waves (2x4), 2-phase dbuf
template<int ACT, int OCHW, int OBF>
__global__ __launch_bounds__(512) void mgemm_a(
    const unsigned short* __restrict__ A, const unsigned short* __restrict__ Wt,
    const float* __restrict__ bias, void* __restrict__ Cv, int N, int K)
{
  __shared__ unsigned short Al[2][128 * 32];   // 16 KB
  __shared__ unsigned short Bl[2][256 * 32];   // 32 KB
  const int tid  = threadIdx.x;
  const int lane = tid & 63;
  const int wid  = tid >> 6;
  const int wr = wid >> 2, wc = wid & 3;       // 2x4 waves, 64x64 each
  const int nbx = N >> 8;
  const int bid = blockIdx.x;
  const int lt  = (bid & 7) * ((int)gridDim.x >> 3) + (bid >> 3);
  const int bn  = (lt % nbx) * 256, bm = (lt / nbx) * 128;

  f32x4 acc[4][4];
  #pragma unroll
  for (int m = 0; m < 4; m++)
    #pragma unroll
    for (int n = 0; n < 4; n++)
      acc[m][n] = (f32x4){0.f, 0.f, 0.f, 0.f};

  const int srow = tid >> 2;                   // 0..127
  const int cs   = (tid & 3) ^ rowf(srow);
  const unsigned short* aSrc  = A  + (size_t)(bm + srow) * K + cs * 8;
  const unsigned short* bSrc0 = Wt + (size_t)(bn + srow) * K + cs * 8;
  const unsigned short* bSrc1 = Wt + (size_t)(bn + srow + 128) * K + cs * 8;

  const int slotx = (lane >> 4) ^ (lane & 3) ^ ((lane >> 2) & 3);
  const int aoff = (wr*64 + (lane & 15)) * 64 + slotx * 16;
  const int boff = (wc*64 + (lane & 15)) * 64 + slotx * 16;

  {
    gload16(aSrc,  (char*)Al[0] + tid * 16);
    gload16(bSrc0, (char*)Bl[0] + tid * 16);
    gload16(bSrc1, (char*)Bl[0] + tid * 16 + 8192);
  }
  __syncthreads();

  const int nt = K >> 5;
  int cur = 0;
  for (int t = 0; t < nt; ++t) {
    if (t + 1 < nt) {
      int k0 = (t + 1) << 5;
      gload16(aSrc + k0,  (char*)Al[cur ^ 1] + tid * 16);
      gload16(bSrc0 + k0, (char*)Bl[cur ^ 1] + tid * 16);
      gload16(bSrc1 + k0, (char*)Bl[cur ^ 1] + tid * 16 + 8192);
    }
    const char* ab = (const char*)Al[cur] + aoff;
    const char* bbp = (const char*)Bl[cur] + boff;
    s16x8 af[4], bf_[4];
    #pragma unroll
    for (int m = 0; m < 4; m++) af[m]  = *(const s16x8*)(ab + m * 1024);
    #pragma unroll
    for (int n = 0; n < 4; n++) bf_[n] = *(const s16x8*)(bbp + n * 1024);
    #pragma unroll
    for (int m = 0; m < 4; m++)
      #pragma unroll
      for (int n = 0; n < 4; n++)
        acc[m][n] = __builtin_amdgcn_mfma_f32_16x16x32_bf16(af[m], bf_[n], acc[m][n], 0, 0, 0);
    __syncthreads();
    cur ^= 1;
  }

  float bv[4];
  #pragma unroll
  for (int n = 0; n < 4; n++) bv[n] = bias[bn + wc*64 + n*16 + (lane & 15)];

  #pragma unroll
  for (int m = 0; m < 4; m++) {
    int row0 = bm + wr*64 + m*16 + (lane >> 4) * 4;
    #pragma unroll
    for (int n = 0; n < 4; n++) {
      int col = bn + wc*64 + n*16 + (lane & 15);
      if (OCHW) {
        int bb2 = row0 >> 14, n0 = row0 & (NPB - 1);
        float4 st;
        st.x = acc[m][n][0] + bv[n]; st.y = acc[m][n][1] + bv[n];
        st.z = acc[m][n][2] + bv[n]; st.w = acc[m][n][3] + bv[n];
        *(float4*)((float*)Cv + (size_t)bb2 * E_DIM * NPB + (size_t)col * NPB + n0) = st;
      } else {
        #pragma unroll
        for (int j = 0; j < 4; j++) {
          int row = row0 + j;
          float v = acc[m][n][j] + bv[n];
          if (ACT) v = fgelu(v);
          if (OBF) ((unsigned short*)Cv)[(size_t)row * N + col] = f2bu(v);
          else     ((float*)Cv)[(size_t)row * N + col] = v;
        }
      }
    }
  }
}

// ---------------- bf16 MFMA GEMM + residual + fused LN (or cast), N=256 fixed
template<int LNC>
__global__ __launch_bounds__(512) void mgemm_res(
    const unsigned short* __restrict__ A, const unsigned short* __restrict__ Wt,
    const float* __restrict__ bias, float* __restrict__ seq,
    const float* __restrict__ gamma, const float* __restrict__ beta,
    unsigned short* __restrict__ hb, int K)
{
  __shared__ unsigned short Al[2][64 * 32];    // 8 KB
  __shared__ unsigned short Bl[2][256 * 32];   // 32 KB
  __shared__ float2 ws[64][4];
  const int tid  = threadIdx.x;
  const int lane = tid & 63;
  const int wid  = tid >> 6;
  const int wr = wid >> 2, wc = wid & 3;       // 2x4 waves, 32x64 each
  const int bid = blockIdx.x;
  const int lt  = (bid & 7) * ((int)gridDim.x >> 3) + (bid >> 3);
  const int bm  = lt * 64;

  f32x4 acc[2][4];
  #pragma unroll
  for (int m = 0; m < 2; m++)
    #pragma unroll
    for (int n = 0; n < 4; n++)
      acc[m][n] = (f32x4){0.f, 0.f, 0.f, 0.f};

  const int srow = tid >> 2;
  const int cs   = (tid & 3) ^ rowf(srow);
  const unsigned short* aSrc  = A  + (size_t)(bm + srow) * K + cs * 8;   // tid<256
  const unsigned short* bSrc0 = Wt + (size_t)srow * K + cs * 8;
  const unsigned short* bSrc1 = Wt + (size_t)(srow + 128) * K + cs * 8;

  const int slotx = (lane >> 4) ^ (lane & 3) ^ ((lane >> 2) & 3);
  const int aoff = (wr*32 + (lane & 15)) * 64 + slotx * 16;
  const int boff = (wc*64 + (lane & 15)) * 64 + slotx * 16;

  {
    if (tid < 256) gload16(aSrc, (char*)Al[0] + tid * 16);
    gload16(bSrc0, (char*)Bl[0] + tid * 16);
    gload16(bSrc1, (char*)Bl[0] + tid * 16 + 8192);
  }
  __syncthreads();

  const int nt = K >> 5;
  int cur = 0;
  for (int t = 0; t < nt; ++t) {
    if (t + 1 < nt) {
      int k0 = (t + 1) << 5;
      if (tid < 256) gload16(aSrc + k0, (char*)Al[cur ^ 1] + tid * 16);
      gload16(bSrc0 + k0, (char*)Bl[cur ^ 1] + tid * 16);
      gload16(bSrc1 + k0, (char*)Bl[cur ^ 1] + tid * 16 + 8192);
    }
    const char* ab = (const char*)Al[cur] + aoff;
    const char* bbp = (const char*)Bl[cur] + boff;
    s16x8 af[2], bf_[4];
    #pragma unroll
    for (int m = 0; m < 2; m++) af[m]  = *(const s16x8*)(ab + m * 1024);
    #pragma unroll
    for (int n = 0; n < 4; n++) bf_[n] = *(const s16x8*)(bbp + n * 1024);
    #pragma unroll
    for (int m = 0; m < 2; m++)
      #pragma unroll
      for (int n = 0; n < 4; n++)
        acc[m][n] = __builtin_amdgcn_mfma_f32_16x16x32_bf16(af[m], bf_[n], acc[m][n], 0, 0, 0);
    __syncthreads();
    cur ^= 1;
  }

  const int lc = lane & 15, lg = lane >> 4;
  float bv[4], gv[4], btv[4];
  #pragma unroll
  for (int n = 0; n < 4; n++) {
    int col = wc*64 + n*16 + lc;
    bv[n] = bias[col];
    if (LNC) { gv[n] = gamma[col]; btv[n] = beta[col]; }
  }

  #pragma unroll
  for (int m = 0; m < 2; m++)
    #pragma unroll
    for (int j = 0; j < 4; j++) {
      int row = bm + wr*32 + m*16 + lg*4 + j;
      #pragma unroll
      for (int n = 0; n < 4; n++) {
        int col = wc*64 + n*16 + lc;
        float v = acc[m][n][j] + bv[n] + seq[(size_t)row * 256 + col];
        seq[(size_t)row * 256 + col] = v;
        acc[m][n][j] = v;
      }
    }

  if (LNC) {
    #pragma unroll
    for (int m = 0; m < 2; m++)
      #pragma unroll
      for (int j = 0; j < 4; j++) {
        float s = acc[m][0][j] + acc[m][1][j] + acc[m][2][j] + acc[m][3][j];
        float q = acc[m][0][j]*acc[m][0][j] + acc[m][1][j]*acc[m][1][j]
                + acc[m][2][j]*acc[m][2][j] + acc[m][3][j]*acc[m][3][j];
        s += __shfl_xor(s, 1); q += __shfl_xor(q, 1);
        s += __shfl_xor(s, 2); q += __shfl_xor(q, 2);
        s += __shfl_xor(s, 4); q += __shfl_xor(q, 4);
        s += __shfl_xor(s, 8); q += __shfl_xor(q, 8);
        if (lc == 0) ws[wr*32 + m*16 + lg*4 + j][wc] = (float2){s, q};
      }
    __syncthreads();
  }

  #pragma unroll
  for (int m = 0; m < 2; m++)
    #pragma unroll
    for (int j = 0; j < 4; j++) {
      int r = wr*32 + m*16 + lg*4 + j;
      float mean = 0.f, rstd = 1.f;
      if (LNC) {
        float2 a0 = ws[r][0], a1 = ws[r][1], a2 = ws[r][2], a3 = ws[r][3];
        float s = a0.x + a1.x + a2.x + a3.x;
        float q = a0.y + a1.y + a2.y + a3.y;
        mean = s * (1.0f / 256.0f);
        rstd = rsqrtf(q * (1.0f / 256.0f) - mean * mean + 1e-5f);
      }
      unsigned short* hrow = hb + (size_t)(bm + r) * 256;
      #pragma unroll
      for (int n = 0; n < 4; n++) {
        int col = wc*64 + n*16 + lc;
        float o = LNC ? (acc[m][n][j] - mean) * rstd * gv[n] + btv[n]
                      : acc[m][n][j];
        hrow[col] = f2bu(o);
      }
    }
}

extern "C" void kernel_launch(void* const* d_in, const int* in_sizes, int n_in,
                              void* d_out, int out_size, void* d_ws, size_t ws_size,
                              hipStream_t stream) {
  (void)in_sizes; (void)n_in; (void)out_size; (void)ws_size;
  const float* x      = (const float*)d_in[0];
  const float* in_w   = (const float*)d_in[1];
  const float* in_b   = (const float*)d_in[2];
  const float* pos    = (const float*)d_in[3];
  const float* ln1_g  = (const float*)d_in[4];
  const float* ln1_b  = (const float*)d_in[5];
  const float* qkv_w  = (const float*)d_in[6];
  const float* qkv_b  = (const float*)d_in[7];
  const float* proj_w = (const float*)d_in[8];
  const float* proj_b = (const float*)d_in[9];
  const float* ln2_g  = (const float*)d_in[10];
  const float* ln2_b  = (const float*)d_in[11];
  const float* mlp_w1 = (const float*)d_in[12];
  const float* mlp_b1 = (const float*)d_in[13];
  const float* mlp_w2 = (const float*)d_in[14];
  const float* mlp_b2 = (const float*)d_in[15];
  const float* out_w  = (const float*)d_in[16];
  const float* out_b  = (const float*)d_in[17];
  float* outp = (float*)d_out;

  // workspace layout
  char* p = (char*)d_ws;
  float* seq = (float*)p;                 p += (size_t)M_TOT * E_DIM * 4;   // 32 MB fp32 residual
  unsigned short* bigb = (unsigned short*)p; p += (size_t)M_TOT * 1024 * 2; // 64 MB bf16 (mlp hidden)
  unsigned short* hb = (unsigned short*)p;   p += (size_t)M_TOT * E_DIM * 2;// 16 MB bf16
  unsigned short* wb = (unsigned short*)p;                                  // 6.4 MB bf16 weights
  unsigned short* qkvT = wb;                         // [L][768][256]
  unsigned short* projT = qkvT + 4 * 768 * 256;      // [L][256][256]
  unsigned short* w1T   = projT + 4 * 256 * 256;     // [L][1024][256]
  unsigned short* w2T   = w1T   + 4 * 1024 * 256;    // [L][256][1024]
  unsigned short* outwb = w2T   + 4 * 256 * 1024;    // [256][256] (already [N,K])

  wconv_all<<<3136, 256, 0, stream>>>(qkv_w, proj_w, mlp_w1, mlp_w2, out_w,
                                      qkvT, projT, w1T, w2T, outwb);
  embed_ln<<<1024, 256, 0, stream>>>(x, in_w, in_b, pos, ln1_g, ln1_b, seq, hb);

  for (int i = 0; i < 4; i++) {
    int shifted = i & 1;
    // fused QKV + attention: hb -> hb (in place per window)
    if (shifted) qkv_attn<1><<<512, 512, 0, stream>>>(hb, qkvT + (size_t)i*768*256, qkv_b + i*768, hb);
    else         qkv_attn<0><<<512, 512, 0, stream>>>(hb, qkvT + (size_t)i*768*256, qkv_b + i*768, hb);
    // proj + residual -> seq ; fused LN2 -> hb
    mgemm_res<1><<<512, 512, 0, stream>>>(
        hb, projT + (size_t)i*256*256, proj_b + i*256, seq,
        ln2_g + i*256, ln2_b + i*256, hb, 256);
    // MLP1 + gelu -> bigb bf16 (64x256 tile, high occupancy)
    mgemm_b<1,1><<<2048, 512, 0, stream>>>(
        hb, w1T + (size_t)i*1024*256, mlp_b1 + i*1024, bigb, 1024, 256);
    // MLP2 + residual -> seq ; fused LN1(next) or cast -> hb
    if (i < 3)
      mgemm_res<1><<<512, 512, 0, stream>>>(
          bigb, w2T + (size_t)i*256*1024, mlp_b2 + i*256, seq,
          ln1_g + (i+1)*256, ln1_b + (i+1)*256, hb, 1024);
    else
      mgemm_res<0><<<512, 512, 0, stream>>>(
          bigb, w2T + (size_t)i*256*1024, mlp_b2 + i*256, seq,
          nullptr, nullptr, hb, 1024);
  }

  // final: hb (cast of seq) x out_w^T, channel-major fp32 store
  mgemm_a<0,1,0><<<256, 512, 0, stream>>>(
      hb, outwb, out_b, outp, 256, 256);
}

// Round 24
// 605.765 us; speedup vs baseline: 1.0075x; 1.0075x over previous
//
#include <hip/hip_runtime.h>
#include <hip/hip_bf16.h>
#include <math.h>

// Swin block forward: B=2, IMG=128, E=256, NH=8, HD=32, WS=8, T=64, L=4, HID=1024
#define E_DIM 256
#define NPB 16384           // tokens per batch = 128*128
#define M_TOT 32768         // total tokens

typedef __attribute__((ext_vector_type(4))) float f32x4;
typedef __attribute__((ext_vector_type(8))) short s16x8;

__device__ inline unsigned short f2bu(float f) {       // fp32 -> bf16 via native cvt
  __hip_bfloat16 h = __float2bfloat16(f);
  return *reinterpret_cast<unsigned short*>(&h);
}
__device__ inline float bu2f(unsigned short u) {
  union { unsigned int i; float f; } x; x.i = ((unsigned int)u) << 16; return x.f;
}
__device__ inline void gload16(const void* g, void* l) {
  __builtin_amdgcn_global_load_lds(
      (const __attribute__((address_space(1))) void*)g,
      (__attribute__((address_space(3))) void*)l, 16, 0, 0);
}
// fast gelu (tanh form)
__device__ inline float fgelu(float v) {
  float u2 = 2.0f * v * (0.7978845608f + 0.0356774081f * v * v);
  u2 = fminf(u2, 30.0f);
  float e = __expf(u2);
  return v * (e / (e + 1.0f));
}

// ---------------- ALL weight conversions in ONE dispatch (3136 blocks)
__global__ __launch_bounds__(256) void wconv_all(
    const float* __restrict__ qkv_w, const float* __restrict__ proj_w,
    const float* __restrict__ w1,    const float* __restrict__ w2,
    const float* __restrict__ outw,
    unsigned short* __restrict__ qkvT, unsigned short* __restrict__ projT,
    unsigned short* __restrict__ w1T,  unsigned short* __restrict__ w2T,
    unsigned short* __restrict__ outwb)
{
  int bid = blockIdx.x;
  if (bid >= 3072) {                      // out_w cast
    int idx = (bid - 3072) * 1024 + threadIdx.x * 4;
    float4 v = *(const float4*)(outw + idx);
    ushort4 u; u.x = f2bu(v.x); u.y = f2bu(v.y); u.z = f2bu(v.z); u.w = f2bu(v.w);
    *(ushort4*)(outwb + idx) = u;
    return;
  }
  int layer = bid / 768, r = bid % 768;
  const float* W; unsigned short* Wt; int K, N, txt, tile;
  if (r < 192)      { W = qkv_w  + (size_t)layer*196608; Wt = qkvT + (size_t)layer*196608; K=256;  N=768;  txt=24; tile=r; }
  else if (r < 256) { W = proj_w + (size_t)layer*65536;  Wt = projT+ (size_t)layer*65536;  K=256;  N=256;  txt=8;  tile=r-192; }
  else if (r < 512) { W = w1     + (size_t)layer*262144; Wt = w1T  + (size_t)layer*262144; K=256;  N=1024; txt=32; tile=r-256; }
  else              { W = w2     + (size_t)layer*262144; Wt = w2T  + (size_t)layer*262144; K=1024; N=256;  txt=8;  tile=r-512; }
  int nb = (tile % txt) * 32, kb = (tile / txt) * 32;
  __shared__ float t[32][33];
  int tx = threadIdx.x & 31, ty = threadIdx.x >> 5;
  #pragma unroll
  for (int i = 0; i < 32; i += 8)
    t[ty + i][tx] = W[(size_t)(kb + ty + i) * N + nb + tx];
  __syncthreads();
  #pragma unroll
  for (int i = 0; i < 32; i += 8)
    Wt[(size_t)(nb + ty + i) * K + kb + tx] = f2bu(t[tx][ty + i]);
}

// ---------------- fused input embed + LN1(layer0)
__global__ __launch_bounds__(256) void embed_ln(
    const float* __restrict__ x, const float* __restrict__ in_w,
    const float* __restrict__ in_b, const float* __restrict__ pos,
    const float* __restrict__ g, const float* __restrict__ bta,
    float* __restrict__ seq, unsigned short* __restrict__ hb)
{
  __shared__ float ld[32][33];
  __shared__ float vbuf[32][260];
  __shared__ float2 st[32];
  const int n0 = blockIdx.x * 32;
  const int b = n0 >> 14, np = n0 & (NPB - 1);
  const int tx = threadIdx.x & 31, ty = threadIdx.x >> 5;

  float x0[4], x1[4], x2[4], sp[4] = {0,0,0,0}, qp[4] = {0,0,0,0};
  #pragma unroll
  for (int i = 0; i < 4; i++) {
    int n = np + ty + 8*i;
    x0[i] = x[(b*3 + 0)*NPB + n];
    x1[i] = x[(b*3 + 1)*NPB + n];
    x2[i] = x[(b*3 + 2)*NPB + n];
  }
  for (int ec = 0; ec < 8; ec++) {
    int e0 = ec * 32;
    #pragma unroll
    for (int i = 0; i < 4; i++)
      ld[ty + 8*i][tx] = pos[(size_t)(e0 + ty + 8*i) * NPB + np + tx];
    __syncthreads();
    #pragma unroll
    for (int i = 0; i < 4; i++) {
      int e = e0 + tx;
      float v = x0[i]*in_w[e*3+0] + x1[i]*in_w[e*3+1] + x2[i]*in_w[e*3+2]
              + in_b[e] + ld[tx][ty + 8*i];
      vbuf[ty + 8*i][e] = v;
      sp[i] += v; qp[i] += v * v;
    }
    __syncthreads();
  }
  #pragma unroll
  for (int i = 0; i < 4; i++) {
    #pragma unroll
    for (int off = 1; off < 32; off <<= 1) {
      sp[i] += __shfl_xor(sp[i], off);
      qp[i] += __shfl_xor(qp[i], off);
    }
    if (tx == 0) st[ty + 8*i] = (float2){sp[i], qp[i]};
  }
  __syncthreads();
  const int token = threadIdx.x >> 3, ch = threadIdx.x & 7;
  float2 sq = st[token];
  float mean = sq.x * (1.0f / 256.0f);
  float rstd = rsqrtf(sq.y * (1.0f / 256.0f) - mean * mean + 1e-5f);
  float* srow = seq + (size_t)(n0 + token) * 256;
  unsigned short* hrow = hb + (size_t)(n0 + token) * 256;
  #pragma unroll
  for (int u = 0; u < 8; u++) {
    int e = ch * 32 + u * 4;
    float4 v = *(float4*)&vbuf[token][e];
    *(float4*)(srow + e) = v;
    float4 gg = *(const float4*)(g + e);
    float4 bb = *(const float4*)(bta + e);
    ushort4 h;
    h.x = f2bu((v.x - mean) * rstd * gg.x + bb.x);
    h.y = f2bu((v.y - mean) * rstd * gg.y + bb.y);
    h.z = f2bu((v.z - mean) * rstd * gg.z + bb.z);
    h.w = f2bu((v.w - mean) * rstd * gg.w + bb.w);
    *(ushort4*)(hrow + e) = h;
  }
}

// swizzle helper: f(row) for chunk-XOR LDS layout
__device__ inline int rowf(int r) { return (r & 3) ^ ((r >> 2) & 3); }

// ---------------- FUSED QKV-GEMM + window attention: one block per window
template<int SHIFT>
__global__ __launch_bounds__(512) void qkv_attn(
    const unsigned short* __restrict__ hbuf, const unsigned short* __restrict__ qkvT,
    const float* __restrict__ qkv_b, unsigned short* __restrict__ hout)
{
  __shared__ unsigned short AQ[32768];   // 64KB: A[2048 chunks] + Q[t][256]; reused as P
  __shared__ unsigned short Ks[16384];   // 32KB: K[t][256] chunk-swizzled
  __shared__ unsigned short Vt[16384];   // 32KB: V^T [h][d 32][t 64] swizzled
  const int tid = threadIdx.x, lane = tid & 63, wc = tid >> 6;
  const int lc = lane & 15, lg = lane >> 4;
  const int wf = blockIdx.x;
  const int b = wf >> 8, win = wf & 255;
  const int wh = win >> 4, ww = win & 15;

  auto tok_of = [&](int t) -> int {
    int hs = wh * 8 + (t >> 3), ws = ww * 8 + (t & 7);
    if (SHIFT) { hs = (hs + 4) & 127; ws = (ws + 4) & 127; }
    return b * NPB + hs * 128 + ws;
  };
  auto reg_of = [&](int t) -> int {
    int hs = wh * 8 + (t >> 3), ws = ww * 8 + (t & 7);
    int a = (hs < 120) ? 0 : ((hs < 124) ? 1 : 2);
    int c = (ws < 120) ? 0 : ((ws < 124) ? 1 : 2);
    return a * 3 + c;
  };

  #pragma unroll
  for (int jj = 0; jj < 4; jj++) {
    int chunk = tid + jj * 512;
    int r = chunk >> 5, c = chunk & 31;
    int cg = (c & 24) | ((c & 7) ^ (r & 7));
    gload16(hbuf + (size_t)tok_of(r) * 256 + cg * 8, (char*)AQ + chunk * 16);
  }
  __syncthreads();

  const int fmap0 = 2*wc, fmap1 = 2*wc+1, fmap2 = 16+2*wc, fmap3 = 17+2*wc,
            fmap4 = 32+2*wc, fmap5 = 33+2*wc;
  int fmap[6] = {fmap0, fmap1, fmap2, fmap3, fmap4, fmap5};
  f32x4 acc[4][6];
  #pragma unroll
  for (int m = 0; m < 4; m++)
    #pragma unroll
    for (int j = 0; j < 6; j++)
      acc[m][j] = (f32x4){0.f, 0.f, 0.f, 0.f};

  const unsigned short* bb[6];
  #pragma unroll
  for (int j = 0; j < 6; j++)
    bb[j] = qkvT + (size_t)(fmap[j] * 16 + lc) * 256 + lg * 8;

  s16x8 bcur[6];
  #pragma unroll
  for (int j = 0; j < 6; j++) bcur[j] = *(const s16x8*)(bb[j]);

  #pragma unroll
  for (int t = 0; t < 8; t++) {
    s16x8 bnext[6];
    if (t < 7) {
      #pragma unroll
      for (int j = 0; j < 6; j++) bnext[j] = *(const s16x8*)(bb[j] + (t + 1) * 32);
    }
    s16x8 aF[4];
    #pragma unroll
    for (int m = 0; m < 4; m++) {
      int r = m * 16 + lc;
      int g = t * 4 + lg;
      int cc = (g & 24) | ((g & 7) ^ (r & 7));
      aF[m] = *(const s16x8*)(AQ + r * 256 + cc * 8);
    }
    #pragma unroll
    for (int m = 0; m < 4; m++)
      #pragma unroll
      for (int j = 0; j < 6; j++)
        acc[m][j] = __builtin_amdgcn_mfma_f32_16x16x32_bf16(aF[m], bcur[j], acc[m][j], 0, 0, 0);
    if (t < 7) {
      #pragma unroll
      for (int j = 0; j < 6; j++) bcur[j] = bnext[j];
    }
  }

  float bv[6];
  #pragma unroll
  for (int j = 0; j < 6; j++) bv[j] = qkv_b[fmap[j] * 16 + lc];
  const float scale = 0.17677669529663687f;

  #pragma unroll
  for (int j = 0; j < 6; j++) {
    int col = fmap[j] * 16 + lc;
    #pragma unroll
    for (int m = 0; m < 4; m++)
      #pragma unroll
      for (int r = 0; r < 4; r++) {
        int t = m * 16 + lg * 4 + r;
        float v = acc[m][j][r] + bv[j];
        if (j < 2) {                         // Q (fold softmax scale)
          int qc = col, c = qc >> 3;
          int cc = (c & 24) | ((c & 7) ^ (t & 7));
          AQ[16384 + t * 256 + cc * 8 + (qc & 7)] = f2bu(v * scale);
        } else if (j < 4) {                  // K
          int kc = col - 256, c = kc >> 3;
          int cc = (c & 24) | ((c & 7) ^ (t & 7));
          Ks[t * 256 + cc * 8 + (kc & 7)] = f2bu(v);
        } else {                             // V transposed: [wc][d][t]
          int d = col - 512 - wc * 32;
          int tc = (t >> 3) ^ (d & 7);
          Vt[wc * 2048 + d * 64 + tc * 8 + (t & 7)] = f2bu(v);
        }
      }
  }

  s16x8 qf[4], kf[4];
  #pragma unroll
  for (int m = 0; m < 4; m++) {
    int t = m * 16 + lc;
    int g = wc * 4 + lg;
    int cc = (g & 24) | ((g & 7) ^ (t & 7));
    qf[m] = *(const s16x8*)(AQ + 16384 + t * 256 + cc * 8);
    kf[m] = *(const s16x8*)(Ks + t * 256 + cc * 8);
  }
  __syncthreads();

  f32x4 sT[4][4];
  #pragma unroll
  for (int m = 0; m < 4; m++)
    #pragma unroll
    for (int qt = 0; qt < 4; qt++) {
      f32x4 z = (f32x4){0.f, 0.f, 0.f, 0.f};
      sT[m][qt] = __builtin_amdgcn_mfma_f32_16x16x32_bf16(kf[m], qf[qt], z, 0, 0, 0);
    }

  int qreg[4], kreg2[16];
  if (SHIFT) {
    #pragma unroll
    for (int qt = 0; qt < 4; qt++) qreg[qt] = reg_of(qt * 16 + lc);
    #pragma unroll
    for (int m = 0; m < 4; m++)
      #pragma unroll
      for (int r = 0; r < 4; r++) kreg2[m * 4 + r] = reg_of(m * 16 + lg * 4 + r);
  }

  unsigned short* Pl = AQ + wc * 4096;
  #pragma unroll
  for (int qt = 0; qt < 4; qt++) {
    float mx = -1e30f;
    #pragma unroll
    for (int m = 0; m < 4; m++)
      #pragma unroll
      for (int r = 0; r < 4; r++) {
        float s = sT[m][qt][r];
        if (SHIFT && qreg[qt] != kreg2[m * 4 + r]) s -= 100.0f;
        sT[m][qt][r] = s;
        mx = fmaxf(mx, s);
      }
    mx = fmaxf(mx, __shfl_xor(mx, 16));
    mx = fmaxf(mx, __shfl_xor(mx, 32));
    float sum = 0.f;
    #pragma unroll
    for (int m = 0; m < 4; m++)
      #pragma unroll
      for (int r = 0; r < 4; r++) {
        float p = __expf(sT[m][qt][r] - mx);
        sT[m][qt][r] = p;
        sum += p;
      }
    sum += __shfl_xor(sum, 16);
    sum += __shfl_xor(sum, 32);
    float inv = 1.0f / sum;
    int q = qt * 16 + lc;
    #pragma unroll
    for (int m = 0; m < 4; m++) {
      ushort4 pk;
      pk.x = f2bu(sT[m][qt][0] * inv);
      pk.y = f2bu(sT[m][qt][1] * inv);
      pk.z = f2bu(sT[m][qt][2] * inv);
      pk.w = f2bu(sT[m][qt][3] * inv);
      *(ushort4*)(Pl + ((q * 64 + m * 16 + lg * 4) ^ ((q & 7) << 3))) = pk;
    }
  }

  f32x4 oacc[4][2];
  #pragma unroll
  for (int qt = 0; qt < 4; qt++)
    #pragma unroll
    for (int n = 0; n < 2; n++)
      oacc[qt][n] = (f32x4){0.f, 0.f, 0.f, 0.f};
  #pragma unroll
  for (int kb = 0; kb < 2; kb++) {
    s16x8 pa[4], vb2[2];
    #pragma unroll
    for (int qt = 0; qt < 4; qt++) {
      int q = qt * 16 + lc;
      pa[qt] = *(const s16x8*)(Pl + ((q * 64 + kb * 32 + lg * 8) ^ ((q & 7) << 3)));
    }
    #pragma unroll
    for (int n = 0; n < 2; n++) {
      int d = n * 16 + lc;
      vb2[n] = *(const s16x8*)(Vt + wc * 2048 + d * 64 + (((kb * 4 + lg) ^ (d & 7)) * 8));
    }
    #pragma unroll
    for (int qt = 0; qt < 4; qt++)
      #pragma unroll
      for (int n = 0; n < 2; n++)
        oacc[qt][n] = __builtin_amdgcn_mfma_f32_16x16x32_bf16(pa[qt], vb2[n], oacc[qt][n], 0, 0, 0);
  }

  #pragma unroll
  for (int qt = 0; qt < 4; qt++)
    #pragma unroll
    for (int r = 0; r < 4; r++) {
      int q = qt * 16 + lg * 4 + r;
      unsigned short* ob = hout + (size_t)tok_of(q) * 256 + wc * 32;
      ob[lc]      = f2bu(oacc[qt][0][r]);
      ob[16 + lc] = f2bu(oacc[qt][1][r]);
    }
}

// ---------------- bf16 MFMA GEMM, 128x256 tile, BK=32, 8 waves (2x4), 2-phase dbuf
template<int ACT, int OCHW, int OBF>
__global__ __launch_bounds__(512) void mgemm_a(
    const unsigned short* __restrict__ A, const unsigned short* __restrict__ Wt,
    const float* __restrict__ bias, void* __restrict__ Cv, int N, int K)
{
  __shared__ unsigned short Al[2][128 * 32];   // 16 KB
  __shared__ unsigned short Bl[2][256 * 32];   // 32 KB
  const int tid  = threadIdx.x;
  const int lane = tid & 63;
  const int wid  = tid >> 6;
  const int wr = wid >> 2, wc = wid & 3;       // 2x4 waves, 64x64 each
  const int nbx = N >> 8;
  const int bid = blockIdx.x;
  const int lt  = (bid & 7) * ((int)gridDim.x >> 3) + (bid >> 3);
  const int bn  = (lt % nbx) * 256, bm = (lt / nbx) * 128;

  f32x4 acc[4][4];
  #pragma unroll
  for (int m = 0; m < 4; m++)
    #pragma unroll
    for (int n = 0; n < 4; n++)
      acc[m][n] = (f32x4){0.f, 0.f, 0.f, 0.f};

  const int srow = tid >> 2;                   // 0..127
  const int cs   = (tid & 3) ^ rowf(srow);
  const unsigned short* aSrc  = A  + (size_t)(bm + srow) * K + cs * 8;
  const unsigned short* bSrc0 = Wt + (size_t)(bn + srow) * K + cs * 8;
  const unsigned short* bSrc1 = Wt + (size_t)(bn + srow + 128) * K + cs * 8;

  const int slotx = (lane >> 4) ^ (lane & 3) ^ ((lane >> 2) & 3);
  const int aoff = (wr*64 + (lane & 15)) * 64 + slotx * 16;
  const int boff = (wc*64 + (lane & 15)) * 64 + slotx * 16;

  {
    gload16(aSrc,  (char*)Al[0] + tid * 16);
    gload16(bSrc0, (char*)Bl[0] + tid * 16);
    gload16(bSrc1, (char*)Bl[0] + tid * 16 + 8192);
  }
  __syncthreads();

  const int nt = K >> 5;
  int cur = 0;
  for (int t = 0; t < nt; ++t) {
    if (t + 1 < nt) {
      int k0 = (t + 1) << 5;
      gload16(aSrc + k0,  (char*)Al[cur ^ 1] + tid * 16);
      gload16(bSrc0 + k0, (char*)Bl[cur ^ 1] + tid * 16);
      gload16(bSrc1 + k0, (char*)Bl[cur ^ 1] + tid * 16 + 8192);
    }
    const char* ab = (const char*)Al[cur] + aoff;
    const char* bbp = (const char*)Bl[cur] + boff;
    s16x8 af[4], bf_[4];
    #pragma unroll
    for (int m = 0; m < 4; m++) af[m]  = *(const s16x8*)(ab + m * 1024);
    #pragma unroll
    for (int n = 0; n < 4; n++) bf_[n] = *(const s16x8*)(bbp + n * 1024);
    #pragma unroll
    for (int m = 0; m < 4; m++)
      #pragma unroll
      for (int n = 0; n < 4; n++)
        acc[m][n] = __builtin_amdgcn_mfma_f32_16x16x32_bf16(af[m], bf_[n], acc[m][n], 0, 0, 0);
    __syncthreads();
    cur ^= 1;
  }

  float bv[4];
  #pragma unroll
  for (int n = 0; n < 4; n++) bv[n] = bias[bn + wc*64 + n*16 + (lane & 15)];

  #pragma unroll
  for (int m = 0; m < 4; m++) {
    int row0 = bm + wr*64 + m*16 + (lane >> 4) * 4;
    #pragma unroll
    for (int n = 0; n < 4; n++) {
      int col = bn + wc*64 + n*16 + (lane & 15);
      if (OCHW) {
        int bb2 = row0 >> 14, n0 = row0 & (NPB - 1);
        float4 st;
        st.x = acc[m][n][0] + bv[n]; st.y = acc[m][n][1] + bv[n];
        st.z = acc[m][n][2] + bv[n]; st.w = acc[m][n][3] + bv[n];
        *(float4*)((float*)Cv + (size_t)bb2 * E_DIM * NPB + (size_t)col * NPB + n0) = st;
      } else {
        #pragma unroll
        for (int j = 0; j < 4; j++) {
          int row = row0 + j;
          float v = acc[m][n][j] + bv[n];
          if (ACT) v = fgelu(v);
          if (OBF) ((unsigned short*)Cv)[(size_t)row * N + col] = f2bu(v);
          else     ((float*)Cv)[(size_t)row * N + col] = v;
        }
      }
    }
  }
}

// ---------------- bf16 MFMA GEMM + residual + fused LN (or cast), N=256 fixed
template<int LNC>
__global__ __launch_bounds__(512) void mgemm_res(
    const unsigned short* __restrict__ A, const unsigned short* __restrict__ Wt,
    const float* __restrict__ bias, float* __restrict__ seq,
    const float* __restrict__ gamma, const float* __restrict__ beta,
    unsigned short* __restrict__ hb, int K)
{
  __shared__ unsigned short Al[2][64 * 32];    // 8 KB
  __shared__ unsigned short Bl[2][256 * 32];   // 32 KB
  __shared__ float2 ws[64][4];
  const int tid  = threadIdx.x;
  const int lane = tid & 63;
  const int wid  = tid >> 6;
  const int wr = wid >> 2, wc = wid & 3;       // 2x4 waves, 32x64 each
  const int bid = blockIdx.x;
  const int lt  = (bid & 7) * ((int)gridDim.x >> 3) + (bid >> 3);
  const int bm  = lt * 64;

  f32x4 acc[2][4];
  #pragma unroll
  for (int m = 0; m < 2; m++)
    #pragma unroll
    for (int n = 0; n < 4; n++)
      acc[m][n] = (f32x4){0.f, 0.f, 0.f, 0.f};

  const int srow = tid >> 2;
  const int cs   = (tid & 3) ^ rowf(srow);
  const unsigned short* aSrc  = A  + (size_t)(bm + srow) * K + cs * 8;   // tid<256
  const unsigned short* bSrc0 = Wt + (size_t)srow * K + cs * 8;
  const unsigned short* bSrc1 = Wt + (size_t)(srow + 128) * K + cs * 8;

  const int slotx = (lane >> 4) ^ (lane & 3) ^ ((lane >> 2) & 3);
  const int aoff = (wr*32 + (lane & 15)) * 64 + slotx * 16;
  const int boff = (wc*64 + (lane & 15)) * 64 + slotx * 16;

  {
    if (tid < 256) gload16(aSrc, (char*)Al[0] + tid * 16);
    gload16(bSrc0, (char*)Bl[0] + tid * 16);
    gload16(bSrc1, (char*)Bl[0] + tid * 16 + 8192);
  }
  __syncthreads();

  const int nt = K >> 5;
  int cur = 0;
  for (int t = 0; t < nt; ++t) {
    if (t + 1 < nt) {
      int k0 = (t + 1) << 5;
      if (tid < 256) gload16(aSrc + k0, (char*)Al[cur ^ 1] + tid * 16);
      gload16(bSrc0 + k0, (char*)Bl[cur ^ 1] + tid * 16);
      gload16(bSrc1 + k0, (char*)Bl[cur ^ 1] + tid * 16 + 8192);
    }
    const char* ab = (const char*)Al[cur] + aoff;
    const char* bbp = (const char*)Bl[cur] + boff;
    s16x8 af[2], bf_[4];
    #pragma unroll
    for (int m = 0; m < 2; m++) af[m]  = *(const s16x8*)(ab + m * 1024);
    #pragma unroll
    for (int n = 0; n < 4; n++) bf_[n] = *(const s16x8*)(bbp + n * 1024);
    #pragma unroll
    for (int m = 0; m < 2; m++)
      #pragma unroll
      for (int n = 0; n < 4; n++)
        acc[m][n] = __builtin_amdgcn_mfma_f32_16x16x32_bf16(af[m], bf_[n], acc[m][n], 0, 0, 0);
    __syncthreads();
    cur ^= 1;
  }

  const int lc = lane & 15, lg = lane >> 4;
  float bv[4], gv[4], btv[4];
  #pragma unroll
  for (int n = 0; n < 4; n++) {
    int col = wc*64 + n*16 + lc;
    bv[n] = bias[col];
    if (LNC) { gv[n] = gamma[col]; btv[n] = beta[col]; }
  }

  #pragma unroll
  for (int m = 0; m < 2; m++)
    #pragma unroll
    for (int j = 0; j < 4; j++) {
      int row = bm + wr*32 + m*16 + lg*4 + j;
      #pragma unroll
      for (int n = 0; n < 4; n++) {
        int col = wc*64 + n*16 + lc;
        float v = acc[m][n][j] + bv[n] + seq[(size_t)row * 256 + col];
        seq[(size_t)row * 256 + col] = v;
        acc[m][n][j] = v;
      }
    }

  if (LNC) {
    #pragma unroll
    for (int m = 0; m < 2; m++)
      #pragma unroll
      for (int j = 0; j < 4; j++) {
        float s = acc[m][0][j] + acc[m][1][j] + acc[m][2][j] + acc[m][3][j];
        float q = acc[m][0][j]*acc[m][0][j] + acc[m][1][j]*acc[m][1][j]
                + acc[m][2][j]*acc[m][2][j] + acc[m][3][j]*acc[m][3][j];
        s += __shfl_xor(s, 1); q += __shfl_xor(q, 1);
        s += __shfl_xor(s, 2); q += __shfl_xor(q, 2);
        s += __shfl_xor(s, 4); q += __shfl_xor(q, 4);
        s += __shfl_xor(s, 8); q += __shfl_xor(q, 8);
        if (lc == 0) ws[wr*32 + m*16 + lg*4 + j][wc] = (float2){s, q};
      }
    __syncthreads();
  }

  #pragma unroll
  for (int m = 0; m < 2; m++)
    #pragma unroll
    for (int j = 0; j < 4; j++) {
      int r = wr*32 + m*16 + lg*4 + j;
      float mean = 0.f, rstd = 1.f;
      if (LNC) {
        float2 a0 = ws[r][0], a1 = ws[r][1], a2 = ws[r][2], a3 = ws[r][3];
        float s = a0.x + a1.x + a2.x + a3.x;
        float q = a0.y + a1.y + a2.y + a3.y;
        mean = s * (1.0f / 256.0f);
        rstd = rsqrtf(q * (1.0f / 256.0f) - mean * mean + 1e-5f);
      }
      unsigned short* hrow = hb + (size_t)(bm + r) * 256;
      #pragma unroll
      for (int n = 0; n < 4; n++) {
        int col = wc*64 + n*16 + lc;
        float o = LNC ? (acc[m][n][j] - mean) * rstd * gv[n] + btv[n]
                      : acc[m][n][j];
        hrow[col] = f2bu(o);
      }
    }
}

extern "C" void kernel_launch(void* const* d_in, const int* in_sizes, int n_in,
                              void* d_out, int out_size, void* d_ws, size_t ws_size,
                              hipStream_t stream) {
  (void)in_sizes; (void)n_in; (void)out_size; (void)ws_size;
  const float* x      = (const float*)d_in[0];
  const float* in_w   = (const float*)d_in[1];
  const float* in_b   = (const float*)d_in[2];
  const float* pos    = (const float*)d_in[3];
  const float* ln1_g  = (const float*)d_in[4];
  const float* ln1_b  = (const float*)d_in[5];
  const float* qkv_w  = (const float*)d_in[6];
  const float* qkv_b  = (const float*)d_in[7];
  const float* proj_w = (const float*)d_in[8];
  const float* proj_b = (const float*)d_in[9];
  const float* ln2_g  = (const float*)d_in[10];
  const float* ln2_b  = (const float*)d_in[11];
  const float* mlp_w1 = (const float*)d_in[12];
  const float* mlp_b1 = (const float*)d_in[13];
  const float* mlp_w2 = (const float*)d_in[14];
  const float* mlp_b2 = (const float*)d_in[15];
  const float* out_w  = (const float*)d_in[16];
  const float* out_b  = (const float*)d_in[17];
  float* outp = (float*)d_out;

  // workspace layout
  char* p = (char*)d_ws;
  float* seq = (float*)p;                 p += (size_t)M_TOT * E_DIM * 4;   // 32 MB fp32 residual
  unsigned short* bigb = (unsigned short*)p; p += (size_t)M_TOT * 1024 * 2; // 64 MB bf16 (mlp hidden)
  unsigned short* hb = (unsigned short*)p;   p += (size_t)M_TOT * E_DIM * 2;// 16 MB bf16
  unsigned short* wb = (unsigned short*)p;                                  // 6.4 MB bf16 weights
  unsigned short* qkvT = wb;                         // [L][768][256]
  unsigned short* projT = qkvT + 4 * 768 * 256;      // [L][256][256]
  unsigned short* w1T   = projT + 4 * 256 * 256;     // [L][1024][256]
  unsigned short* w2T   = w1T   + 4 * 1024 * 256;    // [L][256][1024]
  unsigned short* outwb = w2T   + 4 * 256 * 1024;    // [256][256] (already [N,K])

  wconv_all<<<3136, 256, 0, stream>>>(qkv_w, proj_w, mlp_w1, mlp_w2, out_w,
                                      qkvT, projT, w1T, w2T, outwb);
  embed_ln<<<1024, 256, 0, stream>>>(x, in_w, in_b, pos, ln1_g, ln1_b, seq, hb);

  for (int i = 0; i < 4; i++) {
    int shifted = i & 1;
    // fused QKV + attention: hb -> hb (in place per window)
    if (shifted) qkv_attn<1><<<512, 512, 0, stream>>>(hb, qkvT + (size_t)i*768*256, qkv_b + i*768, hb);
    else         qkv_attn<0><<<512, 512, 0, stream>>>(hb, qkvT + (size_t)i*768*256, qkv_b + i*768, hb);
    // proj + residual -> seq ; fused LN2 -> hb
    mgemm_res<1><<<512, 512, 0, stream>>>(
        hb, projT + (size_t)i*256*256, proj_b + i*256, seq,
        ln2_g + i*256, ln2_b + i*256, hb, 256);
    // MLP1 + gelu -> bigb bf16
    mgemm_a<1,0,1><<<1024, 512, 0, stream>>>(
        hb, w1T + (size_t)i*1024*256, mlp_b1 + i*1024, bigb, 1024, 256);
    // MLP2 + residual -> seq ; fused LN1(next) or cast -> hb
    if (i < 3)
      mgemm_res<1><<<512, 512, 0, stream>>>(
          bigb, w2T + (size_t)i*256*1024, mlp_b2 + i*256, seq,
          ln1_g + (i+1)*256, ln1_b + (i+1)*256, hb, 1024);
    else
      mgemm_res<0><<<512, 512, 0, stream>>>(
          bigb, w2T + (size_t)i*256*1024, mlp_b2 + i*256, seq,
          nullptr, nullptr, hb, 1024);
  }

  // final: hb (cast of seq) x out_w^T, channel-major fp32 store
  mgemm_a<0,1,0><<<256, 512, 0, stream>>>(
      hb, outwb, out_b, outp, 256, 256);
}